// Round 22
// baseline (138.405 us; speedup 1.0000x reference)
//
#include <hip/hip_runtime.h>
#include <math.h>

#define D_MODEL 1024
#define NUM_HEADS 16
#define DK 64
#define BATCH 2
#define SEQ 2048

using f32x4  = __attribute__((ext_vector_type(4))) float;
using f16x8  = __attribute__((ext_vector_type(8))) _Float16;

__device__ __forceinline__ void gl_lds16(const void* g, void* l) {
    __builtin_amdgcn_global_load_lds(
        (const __attribute__((address_space(1))) void*)g,
        (__attribute__((address_space(3))) void*)l, 16, 0, 0);
}

// ---------------------------------------------------------------------------
// Per-batch prefix scan of mask: pos[b][s] = #valid keys before s, nc[b]=count
// ---------------------------------------------------------------------------
__global__ __launch_bounds__(256) void mask_scan_kernel(
    const int* __restrict__ mask, int* __restrict__ pos, int* __restrict__ nc)
{
    const int b = blockIdx.x;
    const int tid = threadIdx.x;
    __shared__ int sums[256];
    int v[8]; int cnt = 0;
    const int base = b * SEQ + tid * 8;
    #pragma unroll
    for (int e = 0; e < 8; ++e) { v[e] = (mask[base + e] != 0) ? 1 : 0; cnt += v[e]; }
    sums[tid] = cnt;
    __syncthreads();
    for (int off = 1; off < 256; off <<= 1) {
        int t = (tid >= off) ? sums[tid - off] : 0;
        __syncthreads();
        sums[tid] += t;
        __syncthreads();
    }
    int run = sums[tid] - cnt;           // exclusive prefix
    #pragma unroll
    for (int e = 0; e < 8; ++e) { pos[base + e] = run; run += v[e]; }
    if (tid == 255) nc[b] = sums[255];
}

// ---------------------------------------------------------------------------
// ALL conversions in one dispatch. fp32 [rows][1024] -> fp16 [rows][1024],
// row-XOR swizzle baked in (stored 16B block ss = logical ss ^ (drow&7)).
// y=0..3: weights (rows=1024); y=4: query; y=5/6: key_/value row-compacted.
// grid = (2048, 7); weight streams early-exit past 512 blocks.
// ---------------------------------------------------------------------------
__global__ __launch_bounds__(256) void conv_all_kernel(
    const float* Wq, const float* Wk, const float* Wv, const float* Wo,
    const float* query, const float* key_, const float* value,
    _Float16* w2q, _Float16* w2k, _Float16* w2v, _Float16* w2o,
    _Float16* aq, _Float16* ak, _Float16* av,
    const int* __restrict__ mask, const int* __restrict__ pos)
{
    const int y = blockIdx.y;
    const float* src; _Float16* dst; int rows; bool compact = false;
    switch (y) {
        case 0: src = Wq;    dst = w2q; rows = 1024; break;
        case 1: src = Wk;    dst = w2k; rows = 1024; break;
        case 2: src = Wv;    dst = w2v; rows = 1024; break;
        case 3: src = Wo;    dst = w2o; rows = 1024; break;
        case 4: src = query; dst = aq;  rows = 4096; break;
        case 5: src = key_;  dst = ak;  rows = 4096; compact = true; break;
        default: src = value; dst = av; rows = 4096; compact = true; break;
    }
    const int id = blockIdx.x * 256 + threadIdx.x;
    if (id >= rows * 128) return;
    const int row = id >> 7;
    int drow = row;
    if (compact) {
        if (!mask[row]) return;
        drow = (row >> 11) * SEQ + pos[row];
    }
    const int s  = id & 127;             // 16B block (8 f16) in [0,128)
    const int g  = s >> 3, ss = s & 7;
    const int lb = ss ^ (drow & 7);

    const float* p = src + (size_t)row * 1024 + g * 64 + lb * 8;
    const float4 a = *(const float4*)p;
    const float4 bq = *(const float4*)(p + 4);
    f16x8 o;
    o[0] = (_Float16)a.x;  o[1] = (_Float16)a.y;
    o[2] = (_Float16)a.z;  o[3] = (_Float16)a.w;
    o[4] = (_Float16)bq.x; o[5] = (_Float16)bq.y;
    o[6] = (_Float16)bq.z; o[7] = (_Float16)bq.w;
    *(f16x8*)&dst[(size_t)drow * 1024 + s * 8] = o;
}

// ---------------------------------------------------------------------------
// fp16 MFMA GEMM: K=1024, 16 k-steps, 128x64 tile, 3-buffer LDS + counted
// vmcnt + raw s_barrier (r13/r16/r17-proven pipeline). SEPARATE dispatches
// per MODE (r20: z-merge of heterogeneous GEMMs straggles, ~10us loss).
// MODE epilogue:
//   0: fp32 [M][1024] -> d_out        (output projection)
//   1: Q2  fp16 [bh][s][64] = 0.125*v, block-XOR by s&7
//   2: K2  fp16 [bh][p][64] swz      (rows pre-COMPACTED; store if p<nc)
//   3: VT2 fp16 [bh][d][2048] key-block swz (pre-COMPACTED; store if p<nc)
// MODE 2/3: whole tile early-exits when its 128-row stripe is >= nc[b].
// ---------------------------------------------------------------------------
template <int MODE>
__global__ __launch_bounds__(256) void mfma_gemm_f16_kernel(
    const _Float16* __restrict__ A2, const _Float16* __restrict__ W2,
    const float* __restrict__ bias, float* __restrict__ Cf,
    _Float16* __restrict__ Ch, const int* __restrict__ ncArr)
{
    constexpr int KS = 1024;
    __shared__ f16x8 Asl[3][1024];
    __shared__ f16x8 Bsl[3][512];

    const int bm = blockIdx.x * 128, bn = blockIdx.y * 64;
    if (MODE == 2 || MODE == 3) {
        if ((bm & (SEQ - 1)) >= ncArr[bm >> 11]) return;   // uniform exit
    }

    const int tid = threadIdx.x;
    const int wv = tid >> 6, ln = tid & 63;
    const int wm = wv >> 1, wn = wv & 1;
    const int x = ln & 15, y = ln >> 4;

    f32x4 acc[4][2] = {};

    const _Float16* Ab = A2 + (size_t)bm * KS;
    const _Float16* Bb = W2 + (size_t)bn * KS;
    const int srow = ln >> 3;
    const int scol = (ln & 7) * 8;

    auto stage = [&](int bufi, int kt) {
        #pragma unroll
        for (int c = 0; c < 4; ++c) {
            const int rowb = wv * 32 + c * 8;
            gl_lds16(Ab + (size_t)(rowb + srow) * KS + kt * 64 + scol,
                     &Asl[bufi][rowb << 3]);
        }
        #pragma unroll
        for (int c = 0; c < 2; ++c) {
            const int rowb = wv * 16 + c * 8;
            gl_lds16(Bb + (size_t)(rowb + srow) * KS + kt * 64 + scol,
                     &Bsl[bufi][rowb << 3]);
        }
    };

    stage(0, 0);
    stage(1, 1);

    int buf = 0, sbuf = 2;
    for (int kt = 0; kt < 16; ++kt) {
        if (kt < 15) asm volatile("s_waitcnt vmcnt(6)" ::: "memory");
        else         asm volatile("s_waitcnt vmcnt(0)" ::: "memory");
        __builtin_amdgcn_s_barrier();
        if (kt + 2 < 16) stage(sbuf, kt + 2);
        #pragma unroll
        for (int half = 0; half < 2; ++half) {
            f16x8 af[4], bfr[2];
            #pragma unroll
            for (int mf = 0; mf < 4; ++mf) {
                const int r = wm * 64 + mf * 16 + x;
                af[mf] = Asl[buf][(r << 3) | ((half * 4 + y) ^ (r & 7))];
            }
            #pragma unroll
            for (int nf = 0; nf < 2; ++nf) {
                const int r = wn * 32 + nf * 16 + x;
                bfr[nf] = Bsl[buf][(r << 3) | ((half * 4 + y) ^ (r & 7))];
            }
            #pragma unroll
            for (int mf = 0; mf < 4; ++mf)
                #pragma unroll
                for (int nf = 0; nf < 2; ++nf)
                    acc[mf][nf] = __builtin_amdgcn_mfma_f32_16x16x32_f16(
                        af[mf], bfr[nf], acc[mf][nf], 0, 0, 0);
        }
        buf  = (buf  == 2) ? 0 : buf  + 1;
        sbuf = (sbuf == 2) ? 0 : sbuf + 1;
    }

    // epilogue (C/D: col=lane&15, row=(lane>>4)*4+r)  [m89-verified]
    #pragma unroll
    for (int nf = 0; nf < 2; ++nf) {
        const int n = bn + wn * 32 + nf * 16 + x;
        const float bv = bias[n];
        #pragma unroll
        for (int mf = 0; mf < 4; ++mf) {
            const int mbase = bm + wm * 64 + mf * 16 + y * 4;
            #pragma unroll
            for (int r = 0; r < 4; ++r) {
                const int m = mbase + r;
                const float v = acc[mf][nf][r] + bv;
                const int b = m >> 11, s = m & (SEQ - 1);
                const int hh = n >> 6, dd = n & 63;
                if (MODE == 0) {
                    Cf[(size_t)m * D_MODEL + n] = v;
                } else if (MODE == 1) {
                    const int blk = (dd >> 3) ^ (s & 7), i = dd & 7;
                    Ch[((size_t)((b * NUM_HEADS + hh) * SEQ + s)) * 64 +
                       blk * 8 + i] = (_Float16)(v * 0.125f);
                } else if (MODE == 2) {
                    if (s < ncArr[b]) {          // s IS the compacted index
                        const int blk = (dd >> 3) ^ (s & 7), i = dd & 7;
                        Ch[((size_t)((b * NUM_HEADS + hh) * SEQ + s)) * 64 +
                           blk * 8 + i] = (_Float16)v;
                    }
                } else {
                    if (s < ncArr[b]) {
                        const int tile = s >> 6, w = s & 63;
                        const int blk = (w >> 3) ^ (dd & 7), i = w & 7;
                        Ch[((size_t)((b * NUM_HEADS + hh) * DK + dd)) * SEQ +
                           tile * 64 + blk * 8 + i] = (_Float16)v;
                    }
                }
            }
        }
    }
}

// ---------------------------------------------------------------------------
// All-fp16 MFMA flash attention over COMPACTED keys.
// r21: q-fragment pairing — each wave owns 32 q-rows (2 independent
// fragments with own m/l/ctx), blocks 1024 -> 512. Doubles ILP on the
// serial softmax chain (the VALU bottleneck), halves K/V staging traffic
// and barriers per q-row. Double-buffered staging + counted vmcnt +
// setprio + exact defer-rescale (all r18-r20 proven).
// ---------------------------------------------------------------------------
__global__ __launch_bounds__(256) void attn_mfma_kernel(
    const _Float16* __restrict__ Q2, const _Float16* __restrict__ K2,
    const _Float16* __restrict__ VT2, const int* __restrict__ ncArr,
    _Float16* __restrict__ ACT)
{
    __shared__ __align__(16) _Float16 SM[20480];   // 40 KB
    // buf0: Ks@0 VTs@4096 | buf1: Ks@8192 VTs@12288 | Pw@16384 (4x1024)

    const int tid = threadIdx.x;
    const int wave = tid >> 6, lane = tid & 63;
    const int lo4 = lane & 15, hi4 = lane >> 4;
    _Float16* Pw = SM + 16384 + wave * 1024;

    const int orig = blockIdx.x;                     // 512 blocks
    const int swz = (orig & 7) * 64 + (orig >> 3);   // 512%8==0: bijective
    const int bh = swz >> 4, qblk = swz & 15;        // 128 q-rows per block
    const int b = bh >> 4, h = bh & 15;

    const _Float16* Kb = K2 + (size_t)bh * SEQ * 64;
    const _Float16* Vb = VT2 + (size_t)bh * DK * SEQ;

    const int ncb = ncArr[b];
    const int ntiles = (ncb + 63) >> 6;

    // Two Q fragments per wave: rows qblk*128 + wave*32 + f*16 + lo4
    f16x8 qf[2][2];
    #pragma unroll
    for (int f = 0; f < 2; ++f) {
        const int qr = qblk * 128 + wave * 32 + f * 16 + lo4;
        const _Float16* Q2row = Q2 + (size_t)(bh * SEQ + qr) * 64;
        #pragma unroll
        for (int c = 0; c < 2; ++c)
            qf[f][c] = *(const f16x8*)&Q2row[(((c * 4 + hi4) ^ (qr & 7)) * 8)];
    }

    // 4 loads/thread per tile: Ks (512 x16B) | VTs (512 x16B)
    auto stage_kv = [&](int base, int k0) {
        #pragma unroll
        for (int j = 0; j < 4; ++j) {
            const int g = j * 256 + wave * 64;   // wave-uniform dest base
            const int gi = g + lane;
            const _Float16* src;
            if (gi < 512) {
                src = Kb + (size_t)(k0 + (gi >> 3)) * 64 + (gi & 7) * 8;
            } else {
                const int g2 = gi - 512;
                src = Vb + (size_t)(g2 >> 3) * SEQ + k0 + (g2 & 7) * 8;
            }
            gl_lds16(src, SM + base + (size_t)g * 8);
        }
    };

    f32x4 ctx[2][4] = {};   // per-fragment ctx^T frags
    float m[2] = {-INFINITY, -INFINITY}, l[2] = {0.f, 0.f};

    stage_kv(0, 0);
    for (int t = 0; t < ntiles; ++t) {
        if (t + 1 < ntiles) {
            stage_kv(((t + 1) & 1) * 8192, (t + 1) * 64);  // prefetch next
            asm volatile("s_waitcnt vmcnt(4)" ::: "memory"); // retire tile t
        } else {
            asm volatile("s_waitcnt vmcnt(0)" ::: "memory");
        }
        __builtin_amdgcn_s_barrier();        // tile t visible to all waves

        const _Float16* Ks = SM + (t & 1) * 8192;
        const _Float16* VTs = Ks + 4096;
        const int k0 = t * 64;
        const bool fulltile = (k0 + 64 <= ncb);

        #pragma unroll
        for (int f = 0; f < 2; ++f) {
            // S^T = K . Q^T : rows = key, cols = q
            f32x4 sc[4];
            __builtin_amdgcn_s_setprio(1);
            #pragma unroll
            for (int kt = 0; kt < 4; ++kt) {
                f32x4 s = {0.f, 0.f, 0.f, 0.f};
                const int row = kt * 16 + lo4;
                const int rx = row & 7;
                #pragma unroll
                for (int c = 0; c < 2; ++c) {
                    const f16x8 kf = *(f16x8*)&Ks[row * 64 + (((c * 4 + hi4) ^ rx) * 8)];
                    s = __builtin_amdgcn_mfma_f32_16x16x32_f16(kf, qf[f][c], s, 0, 0, 0);
                }
                sc[kt] = s;
            }
            __builtin_amdgcn_s_setprio(0);

            // row-max; tail tile masks invalid keys (kidx >= ncb) to -1e30
            float cmax = -1e30f;
            if (fulltile) {
                #pragma unroll
                for (int kt = 0; kt < 4; ++kt)
                    #pragma unroll
                    for (int r = 0; r < 4; ++r) cmax = fmaxf(cmax, sc[kt][r]);
            } else {
                #pragma unroll
                for (int kt = 0; kt < 4; ++kt)
                    #pragma unroll
                    for (int r = 0; r < 4; ++r) {
                        const int kidx = k0 + kt * 16 + hi4 * 4 + r;
                        const float sv = (kidx < ncb) ? sc[kt][r] : -1e30f;
                        sc[kt][r] = sv;
                        cmax = fmaxf(cmax, sv);
                    }
            }
            cmax = fmaxf(cmax, __shfl_xor(cmax, 16));
            cmax = fmaxf(cmax, __shfl_xor(cmax, 32));

            // EXACT defer: if no lane's max grew, e1 == 1 -> skip rescale
            const bool grow = __any(cmax > m[f]);   // wave-uniform branch
            const float mold = m[f];
            const float mnew = grow ? fmaxf(m[f], cmax) : m[f];
            m[f] = mnew;

            float ps = 0.f;
            #pragma unroll
            for (int kt = 0; kt < 4; ++kt) {
                const float pv0 = __expf(sc[kt][0] - mnew);  // -1e30 -> 0
                const float pv1 = __expf(sc[kt][1] - mnew);
                const float pv2 = __expf(sc[kt][2] - mnew);
                const float pv3 = __expf(sc[kt][3] - mnew);
                ps += (pv0 + pv1) + (pv2 + pv3);
                union { _Float16 hh[2]; unsigned u; } pk0, pk1;  // fp16 RNE
                pk0.hh[0] = (_Float16)pv0; pk0.hh[1] = (_Float16)pv1;
                pk1.hh[0] = (_Float16)pv2; pk1.hh[1] = (_Float16)pv3;
                const int blk16 = (kt * 2 + (hi4 >> 1)) ^ (lo4 & 7);
                unsigned* dst = (unsigned*)&Pw[lo4 * 64 + blk16 * 8 + (hi4 & 1) * 4];
                dst[0] = pk0.u; dst[1] = pk1.u;
            }
            ps += __shfl_xor(ps, 16);
            ps += __shfl_xor(ps, 32);

            if (grow) {                          // e1==1 exactly when !grow
                const float e1 = __expf(mold - mnew);   // mold=-inf -> 0
                l[f] = l[f] * e1 + ps;
                #pragma unroll
                for (int dt = 0; dt < 4; ++dt)
                    #pragma unroll
                    for (int r = 0; r < 4; ++r) ctx[f][dt][r] *= e1;
            } else {
                l[f] += ps;
            }

            // ctx^T += V^T . P^T  (same-wave LDS RAW ordering)
            __builtin_amdgcn_s_setprio(1);
            #pragma unroll
            for (int c = 0; c < 2; ++c) {
                const f16x8 pf = *(f16x8*)&Pw[lo4 * 64 + (((c * 4 + hi4) ^ (lo4 & 7)) * 8)];
                #pragma unroll
                for (int dt = 0; dt < 4; ++dt) {
                    const int row = dt * 16 + lo4;
                    const f16x8 vf =
                        *(f16x8*)&VTs[row * 64 + (((c * 4 + hi4) ^ (row & 7)) * 8)];
                    ctx[f][dt] = __builtin_amdgcn_mfma_f32_16x16x32_f16(vf, pf, ctx[f][dt], 0, 0, 0);
                }
            }
            __builtin_amdgcn_s_setprio(0);
        }

        __builtin_amdgcn_s_barrier();        // all waves done reading buf t
    }

    // epilogue: per fragment — normalize, LDS transpose (stride 68,
    // conflict-free), fused fp16 swizzled activation write
    #pragma unroll
    for (int f = 0; f < 2; ++f) {
        __syncthreads();
        const float inv = (l[f] > 0.f) ? (1.f / l[f]) : 0.f;
        float* OutL = (float*)SM;                    // [64][68] fp32
        #pragma unroll
        for (int dt = 0; dt < 4; ++dt)
            #pragma unroll
            for (int r = 0; r < 4; ++r)
                OutL[(wave * 16 + lo4) * 68 + dt * 16 + hi4 * 4 + r] =
                    ctx[f][dt][r] * inv;
        __syncthreads();
        {
            const int row = tid >> 2, cb = (tid & 3) * 16;
            const int mrow = b * SEQ + qblk * 128 + (row >> 4) * 32 + f * 16
                           + (row & 15);            // global act row
            _Float16* arow = ACT + (size_t)mrow * 1024;
            #pragma unroll
            for (int u = 0; u < 2; ++u) {
                const int lb = (cb >> 3) + u;        // logical 8-col block
                const int ss = lb ^ (mrow & 7);      // stored (swizzled)
                f16x8 hv;
                #pragma unroll
                for (int i = 0; i < 8; ++i)
                    hv[i] = (_Float16)OutL[row * 68 + cb + u * 8 + i];
                *(f16x8*)&arow[h * 64 + ss * 8] = hv;
            }
        }
    }
}

// ---------------------------------------------------------------------------
// fp32 fallback path (only if ws too small)
// ---------------------------------------------------------------------------
template <int SPLIT>
__global__ __launch_bounds__(256) void gemm_bias_kernel(
    const float* __restrict__ A, const float* __restrict__ W,
    const float* __restrict__ bias, float* __restrict__ C,
    int M, int N, int K)
{
    constexpr int TILE = 64, KT = 16;
    __shared__ float As[KT][TILE + 4];
    __shared__ float Ws[KT][TILE + 4];
    const int tid = threadIdx.x;
    const int tx = tid & 15, ty = tid >> 4;
    const int bm = blockIdx.x * TILE, bn = blockIdx.y * TILE;
    const int lrow = tid >> 2, lk4 = (tid & 3) << 2;
    float acc[4][4] = {{0.f}};
    for (int k0 = 0; k0 < K; k0 += KT) {
        const float4 a4 = *(const float4*)&A[(size_t)(bm + lrow) * K + k0 + lk4];
        const float4 w4 = *(const float4*)&W[(size_t)(bn + lrow) * K + k0 + lk4];
        __syncthreads();
        As[lk4 + 0][lrow] = a4.x; As[lk4 + 1][lrow] = a4.y;
        As[lk4 + 2][lrow] = a4.z; As[lk4 + 3][lrow] = a4.w;
        Ws[lk4 + 0][lrow] = w4.x; Ws[lk4 + 1][lrow] = w4.y;
        Ws[lk4 + 2][lrow] = w4.z; Ws[lk4 + 3][lrow] = w4.w;
        __syncthreads();
        #pragma unroll
        for (int kk = 0; kk < KT; ++kk) {
            const float4 av = *(const float4*)&As[kk][ty << 2];
            const float4 wv = *(const float4*)&Ws[kk][tx << 2];
            acc[0][0] += av.x * wv.x; acc[0][1] += av.x * wv.y; acc[0][2] += av.x * wv.z; acc[0][3] += av.x * wv.w;
            acc[1][0] += av.y * wv.x; acc[1][1] += av.y * wv.y; acc[1][2] += av.y * wv.z; acc[1][3] += av.y * wv.w;
            acc[2][0] += av.z * wv.x; acc[2][1] += av.z * wv.y; acc[2][2] += av.z * wv.z; acc[2][3] += av.z * wv.w;
            acc[3][0] += av.w * wv.x; acc[3][1] += av.w * wv.y; acc[3][2] += av.w * wv.z; acc[3][3] += av.w * wv.w;
        }
    }
    const float4 bb = *(const float4*)&bias[bn + (tx << 2)];
    #pragma unroll
    for (int i = 0; i < 4; ++i) {
        const int row = bm + (ty << 2) + i;
        float4 o;
        o.x = acc[i][0] + bb.x; o.y = acc[i][1] + bb.y;
        o.z = acc[i][2] + bb.z; o.w = acc[i][3] + bb.w;
        if (SPLIT) {
            const int b = row >> 11, s = row & (SEQ - 1), hh = bn >> 6;
            *(float4*)&C[((size_t)((b * NUM_HEADS + hh) * SEQ + s)) * DK + (tx << 2)] = o;
        } else {
            *(float4*)&C[(size_t)row * N + bn + (tx << 2)] = o;
        }
    }
}

__global__ __launch_bounds__(256, 2) void attn_fp32_kernel(
    const float* __restrict__ Q, const float* __restrict__ K,
    const float* __restrict__ V, const int* __restrict__ mask,
    float* __restrict__ OUT)
{
    const int qb = blockIdx.x, h = blockIdx.y, b = blockIdx.z;
    const int wave = threadIdx.x >> 6, lane = threadIdx.x & 63;
    const int tid = threadIdx.x;
    const int bh = b * NUM_HEADS + h;
    const float* Qb = Q + (size_t)bh * SEQ * DK;
    const float* Kb = K + (size_t)bh * SEQ * DK;
    const float* Vb = V + (size_t)bh * SEQ * DK;
    const int* mb = mask + b * SEQ;
    __shared__ float Ks[64][68];
    __shared__ float Vs[64][68];
    const int row = qb * 256 + wave * 64 + lane;
    float q[DK], ctx[DK];
    #pragma unroll
    for (int d4 = 0; d4 < 16; ++d4) {
        const float4 t = *(const float4*)&Qb[(size_t)row * DK + 4 * d4];
        q[4*d4] = t.x; q[4*d4+1] = t.y; q[4*d4+2] = t.z; q[4*d4+3] = t.w;
        ctx[4*d4] = 0.f; ctx[4*d4+1] = 0.f; ctx[4*d4+2] = 0.f; ctx[4*d4+3] = 0.f;
    }
    float m = -INFINITY, l = 0.f;
    for (int t = 0; t < SEQ / 64; ++t) {
        const int k0 = t * 64;
        const float* Kt = Kb + (size_t)k0 * DK;
        const float* Vt = Vb + (size_t)k0 * DK;
        __syncthreads();
        #pragma unroll
        for (int i = 0; i < 4; ++i) {
            const int f4 = i * 256 + tid;
            const int r = f4 >> 4, c = (f4 & 15) << 2;
            *(float4*)&Ks[r][c] = *(const float4*)&Kt[4 * f4];
            *(float4*)&Vs[r][c] = *(const float4*)&Vt[4 * f4];
        }
        __syncthreads();
        const unsigned long long mbits = __ballot(mb[k0 + lane] != 0);
        if (mbits == 0ULL) continue;
        for (int c0 = 0; c0 < 64; c0 += 16) {
            const unsigned bits = (unsigned)((mbits >> c0) & 0xFFFFULL);
            if (!bits) continue;
            float sc[16];
            #pragma unroll
            for (int j = 0; j < 16; ++j) {
                if (!((bits >> j) & 1u)) { sc[j] = -INFINITY; continue; }
                float a0 = 0.f, a1 = 0.f, a2 = 0.f, a3 = 0.f;
                #pragma unroll
                for (int d4 = 0; d4 < 16; ++d4) {
                    const float4 kv = *(const float4*)&Ks[c0 + j][4 * d4];
                    a0 += q[4*d4] * kv.x; a1 += q[4*d4+1] * kv.y;
                    a2 += q[4*d4+2] * kv.z; a3 += q[4*d4+3] * kv.w;
                }
                sc[j] = ((a0 + a1) + (a2 + a3)) * 0.125f;
            }
            float cmax = sc[0];
            #pragma unroll
            for (int j = 1; j < 16; ++j) cmax = fmaxf(cmax, sc[j]);
            if (cmax > m) {
                const float scale = __expf(m - cmax);
                l *= scale;
                #pragma unroll
                for (int d = 0; d < DK; ++d) ctx[d] *= scale;
                m = cmax;
            }
            #pragma unroll
            for (int j = 0; j < 16; ++j) {
                if (!((bits >> j) & 1u)) continue;
                const float p = __expf(sc[j] - m);
                l += p;
                #pragma unroll
                for (int d4 = 0; d4 < 16; ++d4) {
                    const float4 vv = *(const float4*)&Vs[c0 + j][4 * d4];
                    ctx[4*d4] += p * vv.x; ctx[4*d4+1] += p * vv.y;
                    ctx[4*d4+2] += p * vv.z; ctx[4*d4+3] += p * vv.w;
                }
            }
        }
    }
    const float inv = (l > 0.f) ? (1.f / l) : 0.f;
    float* dst = OUT + ((size_t)(b * SEQ + row)) * D_MODEL + h * DK;
    #pragma unroll
    for (int d4 = 0; d4 < 16; ++d4) {
        float4 o;
        o.x = ctx[4*d4] * inv; o.y = ctx[4*d4+1] * inv;
        o.z = ctx[4*d4+2] * inv; o.w = ctx[4*d4+3] * inv;
        *(float4*)&dst[4 * d4] = o;
    }
}

// ---------------------------------------------------------------------------
extern "C" void kernel_launch(void* const* d_in, const int* in_sizes, int n_in,
                              void* d_out, int out_size, void* d_ws, size_t ws_size,
                              hipStream_t stream)
{
    const float* query = (const float*)d_in[0];
    const float* key_  = (const float*)d_in[1];
    const float* value = (const float*)d_in[2];
    const int*   mask  = (const int*)d_in[3];
    const float* Wq = (const float*)d_in[4];
    const float* bq = (const float*)d_in[5];
    const float* Wk = (const float*)d_in[6];
    const float* bk = (const float*)d_in[7];
    const float* Wv = (const float*)d_in[8];
    const float* bv = (const float*)d_in[9];
    const float* Wo = (const float*)d_in[10];
    const float* bo = (const float*)d_in[11];
    float* out = (float*)d_out;

    const int M = BATCH * SEQ;                            // 4096
    const size_t ACT_B = (size_t)M * 1024 * 2;            // 8.39 MB (fp16)
    const size_t W_B   = (size_t)D_MODEL * 1024 * 2;      // 2.10 MB (fp16)
    const size_t K2_B  = (size_t)32 * SEQ * 64 * 2;       // 8.39 MB
    const size_t VT2_B = (size_t)32 * DK * SEQ * 2;       // 8.39 MB
    const size_t Q2_B  = K2_B;                            // 8.39 MB
    const size_t POS_B = (size_t)BATCH * SEQ * 4 + 256;

    char* base = (char*)d_ws;
    _Float16* actQh = (_Float16*)(base);
    _Float16* actKh = (_Float16*)(base + ACT_B);
    _Float16* actVh = (_Float16*)(base + 2 * ACT_B);
    _Float16* actO  = (_Float16*)(base + 3 * ACT_B);
    _Float16* w2qh  = (_Float16*)(base + 4 * ACT_B);
    _Float16* w2kh  = (_Float16*)((char*)w2qh + W_B);
    _Float16* w2vh  = (_Float16*)((char*)w2kh + W_B);
    _Float16* w2oh  = (_Float16*)((char*)w2vh + W_B);
    _Float16* k2    = (_Float16*)((char*)w2oh + W_B);
    _Float16* vt2   = (_Float16*)((char*)k2 + K2_B);
    _Float16* q2    = (_Float16*)((char*)vt2 + VT2_B);
    int* posArr = (int*)((char*)q2 + Q2_B);
    int* ncArr  = posArr + BATCH * SEQ;
    const size_t need = 4 * ACT_B + 4 * W_B + K2_B + VT2_B + Q2_B + POS_B; // ~67 MB

    if (ws_size >= need) {
        mask_scan_kernel<<<BATCH, 256, 0, stream>>>(mask, posArr, ncArr);

        // ALL 7 conversions in one dispatch (weights + inputs)
        conv_all_kernel<<<dim3(2048, 7), 256, 0, stream>>>(
            Wq, Wk, Wv, Wo, query, key_, value,
            w2qh, w2kh, w2vh, w2oh, actQh, actKh, actVh, mask, posArr);

        dim3 ggrid(M / 128, D_MODEL / 64);                // 32 x 16 = 512 blocks
        mfma_gemm_f16_kernel<2><<<ggrid, 256, 0, stream>>>(
            actKh, w2kh, bk, nullptr, k2, ncArr);
        mfma_gemm_f16_kernel<3><<<ggrid, 256, 0, stream>>>(
            actVh, w2vh, bv, nullptr, vt2, ncArr);
        mfma_gemm_f16_kernel<1><<<ggrid, 256, 0, stream>>>(
            actQh, w2qh, bq, nullptr, q2, ncArr);

        attn_mfma_kernel<<<512, 256, 0, stream>>>(q2, k2, vt2, ncArr, actO);

        mfma_gemm_f16_kernel<0><<<ggrid, 256, 0, stream>>>(
            actO, w2oh, bo, out, nullptr, ncArr);
    } else {
        float* q_ws = (float*)(base);
        float* k_ws = (float*)(base + (size_t)M * D_MODEL * 4);
        float* v_ws = (float*)(base + 2 * (size_t)M * D_MODEL * 4);
        float* c_ws = (float*)(base + 3 * (size_t)M * D_MODEL * 4);
        dim3 ggrid(M / 64, D_MODEL / 64);
        gemm_bias_kernel<1><<<ggrid, 256, 0, stream>>>(query, Wq, bq, q_ws, M, D_MODEL, D_MODEL);
        gemm_bias_kernel<1><<<ggrid, 256, 0, stream>>>(key_,  Wk, bk, k_ws, M, D_MODEL, D_MODEL);
        gemm_bias_kernel<1><<<ggrid, 256, 0, stream>>>(value, Wv, bv, v_ws, M, D_MODEL, D_MODEL);
        dim3 agrid(SEQ / 256, NUM_HEADS, BATCH);
        attn_fp32_kernel<<<agrid, 256, 0, stream>>>(q_ws, k_ws, v_ws, mask, c_ws);
        gemm_bias_kernel<0><<<ggrid, 256, 0, stream>>>(c_ws, Wo, bo, out, M, D_MODEL, D_MODEL);
    }
}

// Round 23
// 130.994 us; speedup vs baseline: 1.0566x; 1.0566x over previous
//
#include <hip/hip_runtime.h>
#include <math.h>

#define D_MODEL 1024
#define NUM_HEADS 16
#define DK 64
#define BATCH 2
#define SEQ 2048

using f32x4  = __attribute__((ext_vector_type(4))) float;
using f16x8  = __attribute__((ext_vector_type(8))) _Float16;

__device__ __forceinline__ void gl_lds16(const void* g, void* l) {
    __builtin_amdgcn_global_load_lds(
        (const __attribute__((address_space(1))) void*)g,
        (__attribute__((address_space(3))) void*)l, 16, 0, 0);
}

// ---------------------------------------------------------------------------
// Per-batch prefix scan of mask: pos[b][s] = #valid keys before s, nc[b]=count
// ---------------------------------------------------------------------------
__global__ __launch_bounds__(256) void mask_scan_kernel(
    const int* __restrict__ mask, int* __restrict__ pos, int* __restrict__ nc)
{
    const int b = blockIdx.x;
    const int tid = threadIdx.x;
    __shared__ int sums[256];
    int v[8]; int cnt = 0;
    const int base = b * SEQ + tid * 8;
    #pragma unroll
    for (int e = 0; e < 8; ++e) { v[e] = (mask[base + e] != 0) ? 1 : 0; cnt += v[e]; }
    sums[tid] = cnt;
    __syncthreads();
    for (int off = 1; off < 256; off <<= 1) {
        int t = (tid >= off) ? sums[tid - off] : 0;
        __syncthreads();
        sums[tid] += t;
        __syncthreads();
    }
    int run = sums[tid] - cnt;           // exclusive prefix
    #pragma unroll
    for (int e = 0; e < 8; ++e) { pos[base + e] = run; run += v[e]; }
    if (tid == 255) nc[b] = sums[255];
}

// ---------------------------------------------------------------------------
// ALL conversions in one dispatch. fp32 [rows][1024] -> fp16 [rows][1024],
// row-XOR swizzle baked in (stored 16B block ss = logical ss ^ (drow&7)).
// y=0..3: weights (rows=1024); y=4: query; y=5/6: key_/value row-compacted.
// grid = (2048, 7); weight streams early-exit past 512 blocks.
// ---------------------------------------------------------------------------
__global__ __launch_bounds__(256) void conv_all_kernel(
    const float* Wq, const float* Wk, const float* Wv, const float* Wo,
    const float* query, const float* key_, const float* value,
    _Float16* w2q, _Float16* w2k, _Float16* w2v, _Float16* w2o,
    _Float16* aq, _Float16* ak, _Float16* av,
    const int* __restrict__ mask, const int* __restrict__ pos)
{
    const int y = blockIdx.y;
    const float* src; _Float16* dst; int rows; bool compact = false;
    switch (y) {
        case 0: src = Wq;    dst = w2q; rows = 1024; break;
        case 1: src = Wk;    dst = w2k; rows = 1024; break;
        case 2: src = Wv;    dst = w2v; rows = 1024; break;
        case 3: src = Wo;    dst = w2o; rows = 1024; break;
        case 4: src = query; dst = aq;  rows = 4096; break;
        case 5: src = key_;  dst = ak;  rows = 4096; compact = true; break;
        default: src = value; dst = av; rows = 4096; compact = true; break;
    }
    const int id = blockIdx.x * 256 + threadIdx.x;
    if (id >= rows * 128) return;
    const int row = id >> 7;
    int drow = row;
    if (compact) {
        if (!mask[row]) return;
        drow = (row >> 11) * SEQ + pos[row];
    }
    const int s  = id & 127;             // 16B block (8 f16) in [0,128)
    const int g  = s >> 3, ss = s & 7;
    const int lb = ss ^ (drow & 7);

    const float* p = src + (size_t)row * 1024 + g * 64 + lb * 8;
    const float4 a = *(const float4*)p;
    const float4 bq = *(const float4*)(p + 4);
    f16x8 o;
    o[0] = (_Float16)a.x;  o[1] = (_Float16)a.y;
    o[2] = (_Float16)a.z;  o[3] = (_Float16)a.w;
    o[4] = (_Float16)bq.x; o[5] = (_Float16)bq.y;
    o[6] = (_Float16)bq.z; o[7] = (_Float16)bq.w;
    *(f16x8*)&dst[(size_t)drow * 1024 + s * 8] = o;
}

// ---------------------------------------------------------------------------
// fp16 MFMA GEMM: K=1024, 16 k-steps, 128x64 tile, 3-buffer LDS + counted
// vmcnt + raw s_barrier (r13/r16/r17-proven pipeline). SEPARATE dispatches
// per MODE (r20: z-merge of heterogeneous GEMMs straggles, ~10us loss).
// MODE epilogue:
//   0: fp32 [M][1024] -> d_out        (output projection)
//   1: Q2  fp16 [bh][s][64] = 0.125*v, block-XOR by s&7
//   2: K2  fp16 [bh][p][64] swz      (rows pre-COMPACTED; store if p<nc)
//   3: VT2 fp16 [bh][d][2048] key-block swz (pre-COMPACTED; store if p<nc)
// MODE 2/3: whole tile early-exits when its 128-row stripe is >= nc[b].
// ---------------------------------------------------------------------------
template <int MODE>
__global__ __launch_bounds__(256) void mfma_gemm_f16_kernel(
    const _Float16* __restrict__ A2, const _Float16* __restrict__ W2,
    const float* __restrict__ bias, float* __restrict__ Cf,
    _Float16* __restrict__ Ch, const int* __restrict__ ncArr)
{
    constexpr int KS = 1024;
    __shared__ f16x8 Asl[3][1024];
    __shared__ f16x8 Bsl[3][512];

    const int bm = blockIdx.x * 128, bn = blockIdx.y * 64;
    if (MODE == 2 || MODE == 3) {
        if ((bm & (SEQ - 1)) >= ncArr[bm >> 11]) return;   // uniform exit
    }

    const int tid = threadIdx.x;
    const int wv = tid >> 6, ln = tid & 63;
    const int wm = wv >> 1, wn = wv & 1;
    const int x = ln & 15, y = ln >> 4;

    f32x4 acc[4][2] = {};

    const _Float16* Ab = A2 + (size_t)bm * KS;
    const _Float16* Bb = W2 + (size_t)bn * KS;
    const int srow = ln >> 3;
    const int scol = (ln & 7) * 8;

    auto stage = [&](int bufi, int kt) {
        #pragma unroll
        for (int c = 0; c < 4; ++c) {
            const int rowb = wv * 32 + c * 8;
            gl_lds16(Ab + (size_t)(rowb + srow) * KS + kt * 64 + scol,
                     &Asl[bufi][rowb << 3]);
        }
        #pragma unroll
        for (int c = 0; c < 2; ++c) {
            const int rowb = wv * 16 + c * 8;
            gl_lds16(Bb + (size_t)(rowb + srow) * KS + kt * 64 + scol,
                     &Bsl[bufi][rowb << 3]);
        }
    };

    stage(0, 0);
    stage(1, 1);

    int buf = 0, sbuf = 2;
    for (int kt = 0; kt < 16; ++kt) {
        if (kt < 15) asm volatile("s_waitcnt vmcnt(6)" ::: "memory");
        else         asm volatile("s_waitcnt vmcnt(0)" ::: "memory");
        __builtin_amdgcn_s_barrier();
        if (kt + 2 < 16) stage(sbuf, kt + 2);
        #pragma unroll
        for (int half = 0; half < 2; ++half) {
            f16x8 af[4], bfr[2];
            #pragma unroll
            for (int mf = 0; mf < 4; ++mf) {
                const int r = wm * 64 + mf * 16 + x;
                af[mf] = Asl[buf][(r << 3) | ((half * 4 + y) ^ (r & 7))];
            }
            #pragma unroll
            for (int nf = 0; nf < 2; ++nf) {
                const int r = wn * 32 + nf * 16 + x;
                bfr[nf] = Bsl[buf][(r << 3) | ((half * 4 + y) ^ (r & 7))];
            }
            #pragma unroll
            for (int mf = 0; mf < 4; ++mf)
                #pragma unroll
                for (int nf = 0; nf < 2; ++nf)
                    acc[mf][nf] = __builtin_amdgcn_mfma_f32_16x16x32_f16(
                        af[mf], bfr[nf], acc[mf][nf], 0, 0, 0);
        }
        buf  = (buf  == 2) ? 0 : buf  + 1;
        sbuf = (sbuf == 2) ? 0 : sbuf + 1;
    }

    // epilogue (C/D: col=lane&15, row=(lane>>4)*4+r)  [m89-verified]
    #pragma unroll
    for (int nf = 0; nf < 2; ++nf) {
        const int n = bn + wn * 32 + nf * 16 + x;
        const float bv = bias[n];
        #pragma unroll
        for (int mf = 0; mf < 4; ++mf) {
            const int mbase = bm + wm * 64 + mf * 16 + y * 4;
            #pragma unroll
            for (int r = 0; r < 4; ++r) {
                const int m = mbase + r;
                const float v = acc[mf][nf][r] + bv;
                const int b = m >> 11, s = m & (SEQ - 1);
                const int hh = n >> 6, dd = n & 63;
                if (MODE == 0) {
                    Cf[(size_t)m * D_MODEL + n] = v;
                } else if (MODE == 1) {
                    const int blk = (dd >> 3) ^ (s & 7), i = dd & 7;
                    Ch[((size_t)((b * NUM_HEADS + hh) * SEQ + s)) * 64 +
                       blk * 8 + i] = (_Float16)(v * 0.125f);
                } else if (MODE == 2) {
                    if (s < ncArr[b]) {          // s IS the compacted index
                        const int blk = (dd >> 3) ^ (s & 7), i = dd & 7;
                        Ch[((size_t)((b * NUM_HEADS + hh) * SEQ + s)) * 64 +
                           blk * 8 + i] = (_Float16)v;
                    }
                } else {
                    if (s < ncArr[b]) {
                        const int tile = s >> 6, w = s & 63;
                        const int blk = (w >> 3) ^ (dd & 7), i = w & 7;
                        Ch[((size_t)((b * NUM_HEADS + hh) * DK + dd)) * SEQ +
                           tile * 64 + blk * 8 + i] = (_Float16)v;
                    }
                }
            }
        }
    }
}

// ---------------------------------------------------------------------------
// All-fp16 MFMA flash attention over COMPACTED keys (r20/r21-proven best:
// 1024 blocks, 16 q-rows/wave, 42.6 us). Double-buffered staging + counted
// vmcnt + raw s_barrier + setprio + exact defer-rescale.
// ---------------------------------------------------------------------------
__global__ __launch_bounds__(256, 4) void attn_mfma_kernel(
    const _Float16* __restrict__ Q2, const _Float16* __restrict__ K2,
    const _Float16* __restrict__ VT2, const int* __restrict__ ncArr,
    _Float16* __restrict__ ACT)
{
    __shared__ __align__(16) _Float16 SM[20480];   // 40 KB
    // buf0: Ks@0 VTs@4096 | buf1: Ks@8192 VTs@12288 | Pw@16384 (4x1024)

    const int tid = threadIdx.x;
    const int wave = tid >> 6, lane = tid & 63;
    const int lo4 = lane & 15, hi4 = lane >> 4;
    _Float16* Pw = SM + 16384 + wave * 1024;

    const int orig = blockIdx.x;
    const int swz = (orig & 7) * 128 + (orig >> 3);  // 1024%8==0: bijective
    const int bh = swz >> 5, qblk = swz & 31;
    const int b = bh >> 4, h = bh & 15;

    const _Float16* Kb = K2 + (size_t)bh * SEQ * 64;
    const _Float16* Vb = VT2 + (size_t)bh * DK * SEQ;

    const int ncb = ncArr[b];
    const int ntiles = (ncb + 63) >> 6;

    // Q fragments (0.125-scaled fp16, XOR-swizzled by s&7)
    const int qr = qblk * 64 + wave * 16 + lo4;
    const _Float16* Q2row = Q2 + (size_t)(bh * SEQ + qr) * 64;
    f16x8 qf[2];
    #pragma unroll
    for (int c = 0; c < 2; ++c)
        qf[c] = *(const f16x8*)&Q2row[(((c * 4 + hi4) ^ (qr & 7)) * 8)];

    // 4 loads/thread per tile: Ks (512 x16B) | VTs (512 x16B)
    auto stage_kv = [&](int base, int k0) {
        #pragma unroll
        for (int j = 0; j < 4; ++j) {
            const int g = j * 256 + wave * 64;   // wave-uniform dest base
            const int gi = g + lane;
            const _Float16* src;
            if (gi < 512) {
                src = Kb + (size_t)(k0 + (gi >> 3)) * 64 + (gi & 7) * 8;
            } else {
                const int g2 = gi - 512;
                src = Vb + (size_t)(g2 >> 3) * SEQ + k0 + (g2 & 7) * 8;
            }
            gl_lds16(src, SM + base + (size_t)g * 8);
        }
    };

    f32x4 ctx[4] = {};   // ctx^T frags: row d = dt*16+hi4*4+r, col q = lo4
    float m = -INFINITY, l = 0.f;

    stage_kv(0, 0);
    for (int t = 0; t < ntiles; ++t) {
        if (t + 1 < ntiles) {
            stage_kv(((t + 1) & 1) * 8192, (t + 1) * 64);  // prefetch next
            asm volatile("s_waitcnt vmcnt(4)" ::: "memory"); // retire tile t
        } else {
            asm volatile("s_waitcnt vmcnt(0)" ::: "memory");
        }
        __builtin_amdgcn_s_barrier();        // tile t visible to all waves

        const _Float16* Ks = SM + (t & 1) * 8192;
        const _Float16* VTs = Ks + 4096;
        const int k0 = t * 64;

        // S^T = K . Q^T : rows = key, cols = q (single fp16 term)
        f32x4 sc[4];
        __builtin_amdgcn_s_setprio(1);
        #pragma unroll
        for (int kt = 0; kt < 4; ++kt) {
            f32x4 s = {0.f, 0.f, 0.f, 0.f};
            const int row = kt * 16 + lo4;
            const int rx = row & 7;
            #pragma unroll
            for (int c = 0; c < 2; ++c) {
                const f16x8 kf = *(f16x8*)&Ks[row * 64 + (((c * 4 + hi4) ^ rx) * 8)];
                s = __builtin_amdgcn_mfma_f32_16x16x32_f16(kf, qf[c], s, 0, 0, 0);
            }
            sc[kt] = s;
        }
        __builtin_amdgcn_s_setprio(0);

        // row-max; tail tile masks invalid keys (kidx >= ncb) to -1e30
        float cmax = -1e30f;
        if (k0 + 64 <= ncb) {
            #pragma unroll
            for (int kt = 0; kt < 4; ++kt)
                #pragma unroll
                for (int r = 0; r < 4; ++r) cmax = fmaxf(cmax, sc[kt][r]);
        } else {
            #pragma unroll
            for (int kt = 0; kt < 4; ++kt)
                #pragma unroll
                for (int r = 0; r < 4; ++r) {
                    const int kidx = k0 + kt * 16 + hi4 * 4 + r;
                    const float sv = (kidx < ncb) ? sc[kt][r] : -1e30f;
                    sc[kt][r] = sv;
                    cmax = fmaxf(cmax, sv);
                }
        }
        cmax = fmaxf(cmax, __shfl_xor(cmax, 16));
        cmax = fmaxf(cmax, __shfl_xor(cmax, 32));

        // EXACT defer: if no lane's max grew, e1 == 1 -> skip rescale work
        const bool grow = __any(cmax > m);   // wave-uniform branch
        const float mold = m;
        const float mnew = grow ? fmaxf(m, cmax) : m;
        m = mnew;

        float ps = 0.f;
        #pragma unroll
        for (int kt = 0; kt < 4; ++kt) {
            const float pv0 = __expf(sc[kt][0] - mnew);  // -1e30 -> exp = 0
            const float pv1 = __expf(sc[kt][1] - mnew);
            const float pv2 = __expf(sc[kt][2] - mnew);
            const float pv3 = __expf(sc[kt][3] - mnew);
            ps += (pv0 + pv1) + (pv2 + pv3);
            union { _Float16 hh[2]; unsigned u; } pk0, pk1;   // fp16 RNE pack
            pk0.hh[0] = (_Float16)pv0; pk0.hh[1] = (_Float16)pv1;
            pk1.hh[0] = (_Float16)pv2; pk1.hh[1] = (_Float16)pv3;
            const int blk16 = (kt * 2 + (hi4 >> 1)) ^ (lo4 & 7);
            unsigned* dst = (unsigned*)&Pw[lo4 * 64 + blk16 * 8 + (hi4 & 1) * 4];
            dst[0] = pk0.u; dst[1] = pk1.u;
        }
        ps += __shfl_xor(ps, 16);
        ps += __shfl_xor(ps, 32);

        if (grow) {                          // e1==1 exactly when !grow
            const float e1 = __expf(mold - mnew);   // mold=-inf -> 0
            l = l * e1 + ps;
            #pragma unroll
            for (int dt = 0; dt < 4; ++dt)
                #pragma unroll
                for (int r = 0; r < 4; ++r) ctx[dt][r] *= e1;
        } else {
            l += ps;
        }

        // ctx^T += V^T . P^T  (same-wave LDS RAW: compiler orders via lgkmcnt)
        __builtin_amdgcn_s_setprio(1);
        #pragma unroll
        for (int c = 0; c < 2; ++c) {
            const f16x8 pf = *(f16x8*)&Pw[lo4 * 64 + (((c * 4 + hi4) ^ (lo4 & 7)) * 8)];
            #pragma unroll
            for (int dt = 0; dt < 4; ++dt) {
                const int row = dt * 16 + lo4;
                const f16x8 vf =
                    *(f16x8*)&VTs[row * 64 + (((c * 4 + hi4) ^ (row & 7)) * 8)];
                ctx[dt] = __builtin_amdgcn_mfma_f32_16x16x32_f16(vf, pf, ctx[dt], 0, 0, 0);
            }
        }
        __builtin_amdgcn_s_setprio(0);

        __builtin_amdgcn_s_barrier();        // all waves done reading buf t
    }

    // epilogue: normalize, LDS transpose (stride 68, conflict-free),
    // fused fp16 swizzled activation write
    __syncthreads();
    const float inv = (l > 0.f) ? (1.f / l) : 0.f;   // l==0: fully masked -> 0
    float* OutL = (float*)SM;                        // [64 q][68] fp32
    #pragma unroll
    for (int dt = 0; dt < 4; ++dt)
        #pragma unroll
        for (int r = 0; r < 4; ++r)
            OutL[(wave * 16 + lo4) * 68 + dt * 16 + hi4 * 4 + r] = ctx[dt][r] * inv;
    __syncthreads();
    {
        const int row = tid >> 2, cb = (tid & 3) * 16;
        const int mrow = b * SEQ + qblk * 64 + row;      // global act row
        _Float16* arow = ACT + (size_t)mrow * 1024;
        #pragma unroll
        for (int u = 0; u < 2; ++u) {
            const int lb = (cb >> 3) + u;                // logical 8-col block
            const int ss = lb ^ (mrow & 7);              // stored (swizzled)
            f16x8 hv;
            #pragma unroll
            for (int i = 0; i < 8; ++i)
                hv[i] = (_Float16)OutL[row * 68 + cb + u * 8 + i];
            *(f16x8*)&arow[h * 64 + ss * 8] = hv;
        }
    }
}

// ---------------------------------------------------------------------------
// fp32 fallback path (only if ws too small)
// ---------------------------------------------------------------------------
template <int SPLIT>
__global__ __launch_bounds__(256) void gemm_bias_kernel(
    const float* __restrict__ A, const float* __restrict__ W,
    const float* __restrict__ bias, float* __restrict__ C,
    int M, int N, int K)
{
    constexpr int TILE = 64, KT = 16;
    __shared__ float As[KT][TILE + 4];
    __shared__ float Ws[KT][TILE + 4];
    const int tid = threadIdx.x;
    const int tx = tid & 15, ty = tid >> 4;
    const int bm = blockIdx.x * TILE, bn = blockIdx.y * TILE;
    const int lrow = tid >> 2, lk4 = (tid & 3) << 2;
    float acc[4][4] = {{0.f}};
    for (int k0 = 0; k0 < K; k0 += KT) {
        const float4 a4 = *(const float4*)&A[(size_t)(bm + lrow) * K + k0 + lk4];
        const float4 w4 = *(const float4*)&W[(size_t)(bn + lrow) * K + k0 + lk4];
        __syncthreads();
        As[lk4 + 0][lrow] = a4.x; As[lk4 + 1][lrow] = a4.y;
        As[lk4 + 2][lrow] = a4.z; As[lk4 + 3][lrow] = a4.w;
        Ws[lk4 + 0][lrow] = w4.x; Ws[lk4 + 1][lrow] = w4.y;
        Ws[lk4 + 2][lrow] = w4.z; Ws[lk4 + 3][lrow] = w4.w;
        __syncthreads();
        #pragma unroll
        for (int kk = 0; kk < KT; ++kk) {
            const float4 av = *(const float4*)&As[kk][ty << 2];
            const float4 wv = *(const float4*)&Ws[kk][tx << 2];
            acc[0][0] += av.x * wv.x; acc[0][1] += av.x * wv.y; acc[0][2] += av.x * wv.z; acc[0][3] += av.x * wv.w;
            acc[1][0] += av.y * wv.x; acc[1][1] += av.y * wv.y; acc[1][2] += av.y * wv.z; acc[1][3] += av.y * wv.w;
            acc[2][0] += av.z * wv.x; acc[2][1] += av.z * wv.y; acc[2][2] += av.z * wv.z; acc[2][3] += av.z * wv.w;
            acc[3][0] += av.w * wv.x; acc[3][1] += av.w * wv.y; acc[3][2] += av.w * wv.z; acc[3][3] += av.w * wv.w;
        }
    }
    const float4 bb = *(const float4*)&bias[bn + (tx << 2)];
    #pragma unroll
    for (int i = 0; i < 4; ++i) {
        const int row = bm + (ty << 2) + i;
        float4 o;
        o.x = acc[i][0] + bb.x; o.y = acc[i][1] + bb.y;
        o.z = acc[i][2] + bb.z; o.w = acc[i][3] + bb.w;
        if (SPLIT) {
            const int b = row >> 11, s = row & (SEQ - 1), hh = bn >> 6;
            *(float4*)&C[((size_t)((b * NUM_HEADS + hh) * SEQ + s)) * DK + (tx << 2)] = o;
        } else {
            *(float4*)&C[(size_t)row * N + bn + (tx << 2)] = o;
        }
    }
}

__global__ __launch_bounds__(256, 2) void attn_fp32_kernel(
    const float* __restrict__ Q, const float* __restrict__ K,
    const float* __restrict__ V, const int* __restrict__ mask,
    float* __restrict__ OUT)
{
    const int qb = blockIdx.x, h = blockIdx.y, b = blockIdx.z;
    const int wave = threadIdx.x >> 6, lane = threadIdx.x & 63;
    const int tid = threadIdx.x;
    const int bh = b * NUM_HEADS + h;
    const float* Qb = Q + (size_t)bh * SEQ * DK;
    const float* Kb = K + (size_t)bh * SEQ * DK;
    const float* Vb = V + (size_t)bh * SEQ * DK;
    const int* mb = mask + b * SEQ;
    __shared__ float Ks[64][68];
    __shared__ float Vs[64][68];
    const int row = qb * 256 + wave * 64 + lane;
    float q[DK], ctx[DK];
    #pragma unroll
    for (int d4 = 0; d4 < 16; ++d4) {
        const float4 t = *(const float4*)&Qb[(size_t)row * DK + 4 * d4];
        q[4*d4] = t.x; q[4*d4+1] = t.y; q[4*d4+2] = t.z; q[4*d4+3] = t.w;
        ctx[4*d4] = 0.f; ctx[4*d4+1] = 0.f; ctx[4*d4+2] = 0.f; ctx[4*d4+3] = 0.f;
    }
    float m = -INFINITY, l = 0.f;
    for (int t = 0; t < SEQ / 64; ++t) {
        const int k0 = t * 64;
        const float* Kt = Kb + (size_t)k0 * DK;
        const float* Vt = Vb + (size_t)k0 * DK;
        __syncthreads();
        #pragma unroll
        for (int i = 0; i < 4; ++i) {
            const int f4 = i * 256 + tid;
            const int r = f4 >> 4, c = (f4 & 15) << 2;
            *(float4*)&Ks[r][c] = *(const float4*)&Kt[4 * f4];
            *(float4*)&Vs[r][c] = *(const float4*)&Vt[4 * f4];
        }
        __syncthreads();
        const unsigned long long mbits = __ballot(mb[k0 + lane] != 0);
        if (mbits == 0ULL) continue;
        for (int c0 = 0; c0 < 64; c0 += 16) {
            const unsigned bits = (unsigned)((mbits >> c0) & 0xFFFFULL);
            if (!bits) continue;
            float sc[16];
            #pragma unroll
            for (int j = 0; j < 16; ++j) {
                if (!((bits >> j) & 1u)) { sc[j] = -INFINITY; continue; }
                float a0 = 0.f, a1 = 0.f, a2 = 0.f, a3 = 0.f;
                #pragma unroll
                for (int d4 = 0; d4 < 16; ++d4) {
                    const float4 kv = *(const float4*)&Ks[c0 + j][4 * d4];
                    a0 += q[4*d4] * kv.x; a1 += q[4*d4+1] * kv.y;
                    a2 += q[4*d4+2] * kv.z; a3 += q[4*d4+3] * kv.w;
                }
                sc[j] = ((a0 + a1) + (a2 + a3)) * 0.125f;
            }
            float cmax = sc[0];
            #pragma unroll
            for (int j = 1; j < 16; ++j) cmax = fmaxf(cmax, sc[j]);
            if (cmax > m) {
                const float scale = __expf(m - cmax);
                l *= scale;
                #pragma unroll
                for (int d = 0; d < DK; ++d) ctx[d] *= scale;
                m = cmax;
            }
            #pragma unroll
            for (int j = 0; j < 16; ++j) {
                if (!((bits >> j) & 1u)) continue;
                const float p = __expf(sc[j] - m);
                l += p;
                #pragma unroll
                for (int d4 = 0; d4 < 16; ++d4) {
                    const float4 vv = *(const float4*)&Vs[c0 + j][4 * d4];
                    ctx[4*d4] += p * vv.x; ctx[4*d4+1] += p * vv.y;
                    ctx[4*d4+2] += p * vv.z; ctx[4*d4+3] += p * vv.w;
                }
            }
        }
    }
    const float inv = (l > 0.f) ? (1.f / l) : 0.f;
    float* dst = OUT + ((size_t)(b * SEQ + row)) * D_MODEL + h * DK;
    #pragma unroll
    for (int d4 = 0; d4 < 16; ++d4) {
        float4 o;
        o.x = ctx[4*d4] * inv; o.y = ctx[4*d4+1] * inv;
        o.z = ctx[4*d4+2] * inv; o.w = ctx[4*d4+3] * inv;
        *(float4*)&dst[4 * d4] = o;
    }
}

// ---------------------------------------------------------------------------
extern "C" void kernel_launch(void* const* d_in, const int* in_sizes, int n_in,
                              void* d_out, int out_size, void* d_ws, size_t ws_size,
                              hipStream_t stream)
{
    const float* query = (const float*)d_in[0];
    const float* key_  = (const float*)d_in[1];
    const float* value = (const float*)d_in[2];
    const int*   mask  = (const int*)d_in[3];
    const float* Wq = (const float*)d_in[4];
    const float* bq = (const float*)d_in[5];
    const float* Wk = (const float*)d_in[6];
    const float* bk = (const float*)d_in[7];
    const float* Wv = (const float*)d_in[8];
    const float* bv = (const float*)d_in[9];
    const float* Wo = (const float*)d_in[10];
    const float* bo = (const float*)d_in[11];
    float* out = (float*)d_out;

    const int M = BATCH * SEQ;                            // 4096
    const size_t ACT_B = (size_t)M * 1024 * 2;            // 8.39 MB (fp16)
    const size_t W_B   = (size_t)D_MODEL * 1024 * 2;      // 2.10 MB (fp16)
    const size_t K2_B  = (size_t)32 * SEQ * 64 * 2;       // 8.39 MB
    const size_t VT2_B = (size_t)32 * DK * SEQ * 2;       // 8.39 MB
    const size_t Q2_B  = K2_B;                            // 8.39 MB
    const size_t POS_B = (size_t)BATCH * SEQ * 4 + 256;

    char* base = (char*)d_ws;
    _Float16* actQh = (_Float16*)(base);
    _Float16* actKh = (_Float16*)(base + ACT_B);
    _Float16* actVh = (_Float16*)(base + 2 * ACT_B);
    _Float16* actO  = (_Float16*)(base + 3 * ACT_B);
    _Float16* w2qh  = (_Float16*)(base + 4 * ACT_B);
    _Float16* w2kh  = (_Float16*)((char*)w2qh + W_B);
    _Float16* w2vh  = (_Float16*)((char*)w2kh + W_B);
    _Float16* w2oh  = (_Float16*)((char*)w2vh + W_B);
    _Float16* k2    = (_Float16*)((char*)w2oh + W_B);
    _Float16* vt2   = (_Float16*)((char*)k2 + K2_B);
    _Float16* q2    = (_Float16*)((char*)vt2 + VT2_B);
    int* posArr = (int*)((char*)q2 + Q2_B);
    int* ncArr  = posArr + BATCH * SEQ;
    const size_t need = 4 * ACT_B + 4 * W_B + K2_B + VT2_B + Q2_B + POS_B; // ~67 MB

    if (ws_size >= need) {
        mask_scan_kernel<<<BATCH, 256, 0, stream>>>(mask, posArr, ncArr);

        // ALL 7 conversions in one dispatch (weights + inputs)
        conv_all_kernel<<<dim3(2048, 7), 256, 0, stream>>>(
            Wq, Wk, Wv, Wo, query, key_, value,
            w2qh, w2kh, w2vh, w2oh, actQh, actKh, actVh, mask, posArr);

        dim3 ggrid(M / 128, D_MODEL / 64);                // 32 x 16 = 512 blocks
        mfma_gemm_f16_kernel<2><<<ggrid, 256, 0, stream>>>(
            actKh, w2kh, bk, nullptr, k2, ncArr);
        mfma_gemm_f16_kernel<3><<<ggrid, 256, 0, stream>>>(
            actVh, w2vh, bv, nullptr, vt2, ncArr);
        mfma_gemm_f16_kernel<1><<<ggrid, 256, 0, stream>>>(
            actQh, w2qh, bq, nullptr, q2, ncArr);

        attn_mfma_kernel<<<1024, 256, 0, stream>>>(q2, k2, vt2, ncArr, actO);

        mfma_gemm_f16_kernel<0><<<ggrid, 256, 0, stream>>>(
            actO, w2oh, bo, out, nullptr, ncArr);
    } else {
        float* q_ws = (float*)(base);
        float* k_ws = (float*)(base + (size_t)M * D_MODEL * 4);
        float* v_ws = (float*)(base + 2 * (size_t)M * D_MODEL * 4);
        float* c_ws = (float*)(base + 3 * (size_t)M * D_MODEL * 4);
        dim3 ggrid(M / 64, D_MODEL / 64);
        gemm_bias_kernel<1><<<ggrid, 256, 0, stream>>>(query, Wq, bq, q_ws, M, D_MODEL, D_MODEL);
        gemm_bias_kernel<1><<<ggrid, 256, 0, stream>>>(key_,  Wk, bk, k_ws, M, D_MODEL, D_MODEL);
        gemm_bias_kernel<1><<<ggrid, 256, 0, stream>>>(value, Wv, bv, v_ws, M, D_MODEL, D_MODEL);
        dim3 agrid(SEQ / 256, NUM_HEADS, BATCH);
        attn_fp32_kernel<<<agrid, 256, 0, stream>>>(q_ws, k_ws, v_ws, mask, c_ws);
        gemm_bias_kernel<0><<<ggrid, 256, 0, stream>>>(c_ws, Wo, bo, out, M, D_MODEL, D_MODEL);
    }
}